// Round 15
// baseline (122.508 us; speedup 1.0000x reference)
//
#include <hip/hip_runtime.h>

#define THREADS 256
#define MU_C  0.1f
#define EPS_C 0.01f

typedef short bf16x8 __attribute__((ext_vector_type(8)));
typedef bf16x8 bf16x8_a __attribute__((may_alias));
typedef float f32x4 __attribute__((ext_vector_type(4)));
typedef f32x4 f32x4_a __attribute__((may_alias));
typedef float f32_a __attribute__((may_alias));
typedef unsigned uint2v __attribute__((ext_vector_type(2)));
typedef uint2v uint2_a __attribute__((may_alias));
typedef unsigned u32_a __attribute__((may_alias));
typedef unsigned short u16_a __attribute__((may_alias));

__device__ __forceinline__ f32x4 MFMA(bf16x8 a, bf16x8 b, f32x4 c) {
    return __builtin_amdgcn_mfma_f32_16x16x32_bf16(a, b, c, 0, 0, 0);
}
__device__ __forceinline__ f32x4 Z4() { f32x4 z = {0.f, 0.f, 0.f, 0.f}; return z; }
#define PRIO_HI() __builtin_amdgcn_s_setprio(1)
#define PRIO_LO() __builtin_amdgcn_s_setprio(0)

// ---- prepacked tile enumeration (1 tile = 64 lanes x 16B = 1 KB in d_ws) ----
#define T_WH1   0
#define T_WH2   8
#define T_WH2T  12
#define T_WH1T  20
#define T_W1JR  24
#define T_W2JR  28
#define T_JMN   36
#define T_JMT   68
#define T_RFN   100
#define T_RFT   132
#define T_W1B   164
#define T_W2B   168
#define T_BMN   176
#define T_BMT   192
#define T_JBN   208
#define T_JBT   209
#define T_RBN   210
#define T_RBT   211
#define T_BBN   212
#define NTILES  213

__device__ __forceinline__ float ftanh(float x) {
    float e = __builtin_amdgcn_exp2f(x * 2.88539008177792681472f);
    return 1.0f - 2.0f * __builtin_amdgcn_rcpf(e + 1.0f);
}
__device__ __forceinline__ short bfrn(float f) {
    unsigned u = __float_as_uint(f);
    return (short)((u + 0x8000u) >> 16);
}
__device__ __forceinline__ float bf2f(unsigned lo16) {
    return __uint_as_float(lo16 << 16);
}
__device__ __forceinline__ unsigned pk2(float lo, float hi) {
    return ((unsigned)(unsigned short)bfrn(hi) << 16) | (unsigned short)bfrn(lo);
}
__device__ __forceinline__ bf16x8 wsB(const short* __restrict__ ws, int tile, int lane) {
    return *reinterpret_cast<const bf16x8*>(ws + (size_t)((tile << 6) + lane) * 8);
}
__device__ __forceinline__ bf16x8 ldsA(const short* base, int strideS, int lane, int k0) {
    return *reinterpret_cast<const bf16x8_a*>(base + (lane & 15) * strideS + k0 + (lane >> 4) * 8);
}

// ==================== weight pre-pack kernel (unchanged) ====================
__global__ __launch_bounds__(256)
void pack_weights(const float* __restrict__ Wh1, const float* __restrict__ bh1,
                  const float* __restrict__ Wh2,
                  const float* __restrict__ W1jr, const float* __restrict__ b1jr,
                  const float* __restrict__ W2jr, const float* __restrict__ W3jr,
                  const float* __restrict__ b3jr,
                  const float* __restrict__ W1b, const float* __restrict__ b1b,
                  const float* __restrict__ W2b, const float* __restrict__ W3b,
                  const float* __restrict__ b3b,
                  short* __restrict__ ws)
{
    const int id = blockIdx.x * 256 + threadIdx.x;
    if (id >= NTILES * 64) return;
    const int tile = id >> 6, lane = id & 63;
    const int j2 = lane & 15, g = lane >> 4;
    bf16x8 f;
#pragma unroll
    for (int jj = 0; jj < 8; ++jj) {
        const int k = g * 8 + jj;
        float x = 0.f;
        if (tile < T_WH2) {
            int n0 = (tile - T_WH1) * 16;
            if (g < 2) x = Wh1[(n0 + j2) * 16 + k];
            else if (k == 16) x = bh1[n0 + j2];
        } else if (tile < T_WH2T) {
            int kt = tile - T_WH2;
            x = Wh2[j2 * 128 + kt * 32 + k];
        } else if (tile < T_WH1T) {
            if (g < 2) x = Wh2[k * 128 + (tile - T_WH2T) * 16 + j2];
        } else if (tile < T_W1JR) {
            int kt = tile - T_WH1T;
            x = Wh1[(kt * 32 + k) * 16 + j2];
        } else if (tile < T_W2JR) {
            int n0 = (tile - T_W1JR) * 16;
            if (g < 2) x = W1jr[(n0 + j2) * 16 + k];
            else if (k == 16) x = b1jr[n0 + j2];
        } else if (tile < T_JMN) {
            int q = tile - T_W2JR; int nt = q >> 1, kt = q & 1;
            x = W2jr[(nt * 16 + j2) * 64 + kt * 32 + k];
        } else if (tile < T_JMT) {
            int q = tile - T_JMN; int n = q >> 1, kt = q & 1;
            x = W3jr[(n * 16 + j2) * 64 + kt * 32 + k];
        } else if (tile < T_RFN) {
            int q = tile - T_JMT; int t = q >> 1, kt = q & 1;
            x = W3jr[(j2 * 16 + t) * 64 + kt * 32 + k];
        } else if (tile < T_RFT) {
            int q = tile - T_RFN; int n = q >> 1, kt = q & 1;
            x = W3jr[(256 + n * 16 + j2) * 64 + kt * 32 + k];
        } else if (tile < T_W1B) {
            int q = tile - T_RFT; int t = q >> 1, kt = q & 1;
            x = W3jr[(256 + j2 * 16 + t) * 64 + kt * 32 + k];
        } else if (tile < T_W2B) {
            int n0 = (tile - T_W1B) * 16;
            if (g < 2) x = W1b[(n0 + j2) * 16 + k];
            else if (k == 16) x = b1b[n0 + j2];
        } else if (tile < T_BMN) {
            int q = tile - T_W2B; int nt = q >> 1, kt = q & 1;
            x = W2b[(nt * 16 + j2) * 64 + kt * 32 + k];
        } else if (tile < T_BMT) {
            int q = tile - T_BMN; int n = q >> 1, kt = q & 1;
            x = W3b[(n * 16 + j2) * 64 + kt * 32 + k];
        } else if (tile < T_JBN) {
            int q = tile - T_BMT; int m = q >> 1, kt = q & 1;
            x = W3b[(j2 * 8 + m) * 64 + kt * 32 + k];
        } else if (tile == T_JBN) {
            if (k < 16) x = b3jr[k * 16 + j2];
        } else if (tile == T_JBT) {
            if (k < 16) x = b3jr[j2 * 16 + k];
        } else if (tile == T_RBN) {
            if (k < 16) x = b3jr[256 + k * 16 + j2];
        } else if (tile == T_RBT) {
            if (k < 16) x = b3jr[256 + j2 * 16 + k];
        } else {  // T_BBN
            if (k < 16 && j2 < 8) x = b3b[k * 8 + j2];
        }
        f[jj] = bfrn(x);
    }
    reinterpret_cast<bf16x8*>(ws)[id] = f;
}

// ==================== main kernel: M=32 rows per wave (r12 champion + T5) ====
struct __align__(16) WaveLds {
    short zt [2][16 * 40];
    short fvt[2][16 * 40];   // fv; reused as gH bf16 tile after step4
    char  act[2][4608];      // t1[16][136]s | {h1t/rft, h2t @2304}
    float gHf[2][16 * 20];
    float uf [2][16 * 9];
};
struct __align__(16) BlockLds {
    WaveLds w[4];
    float bias[256];         // 0 b2jr(64) | 64 b2b(64) | 128 b3b(128)
};

// VGPR ledger: (2,4) -> <=128 budget; r12 unroll depths = 88 regs no-spill.
// r13 unroll4 spilled (reverted); r14 2-wave blocks regressed (reverted).
// T5 setprio around MFMA pairs: waves are barrier-free/phase-diverse (attn-like
// m191 case, not the lockstep m190 null).
__global__ __launch_bounds__(THREADS)
__attribute__((amdgpu_waves_per_eu(2, 4)))
void ph_mfma_kernel(const float* __restrict__ zg, const float* __restrict__ ug,
                    const float* __restrict__ b2jr, const float* __restrict__ b2b,
                    const float* __restrict__ b3b,
                    const short* __restrict__ ws,
                    float* __restrict__ out, int B)
{
    __shared__ BlockLds L;
    const int tid  = threadIdx.x;
    const int lane = tid & 63;
    const int wid  = tid >> 6;
    const int j2   = lane & 15;
    const int g    = lane >> 4;
    const int g4   = g * 4;
    const int rowbase = blockIdx.x * 128 + wid * 32;
    if (blockIdx.x * 128 >= B) return;

    WaveLds& Wv = L.w[wid];
    short* t1p[2] = {(short*)Wv.act[0], (short*)Wv.act[1]};             // stride 136
    short* h1p[2] = {(short*)Wv.act[0], (short*)Wv.act[1]};             // stride 72
    short* h2p[2] = {(short*)(Wv.act[0] + 2304), (short*)(Wv.act[1] + 2304)};
    short* rfp[2] = {(short*)Wv.act[0], (short*)Wv.act[1]};             // stride 40

    // ---- block prologue: biases ----
    if (tid < 256) {
        float v;
        if      (tid < 64)  v = b2jr[tid];
        else if (tid < 128) v = b2b[tid - 64];
        else                v = b3b[tid - 128];
        L.bias[tid] = v;
    }
    // ---- per-wave prologue ----
    if (lane < 16) {
#pragma unroll
        for (int rt = 0; rt < 2; ++rt) {
            u32_a* p = (u32_a*)&Wv.zt[rt][lane * 40 + 16];
            p[0] = 0x00003F80u;
#pragma unroll
            for (int i = 1; i < 8; ++i) p[i] = 0u;
            u32_a* q = (u32_a*)&Wv.fvt[rt][lane * 40 + 16];
#pragma unroll
            for (int i = 0; i < 8; ++i) q[i] = 0u;
        }
    }
    for (int i = lane; i < 256; i += 64) {      // u for both row-tiles
        int rt = i >> 7, r = (i >> 3) & 15, m = i & 7;
        Wv.uf[rt][r * 9 + m] = ug[(size_t)(rowbase + rt * 16 + r) * 8 + m];
    }
    float zReg[2][4];
#pragma unroll
    for (int rt = 0; rt < 2; ++rt) {
        float4 zv = *reinterpret_cast<const float4*>(zg + (size_t)(rowbase + rt * 16 + j2) * 16 + g4);
        zReg[rt][0] = zv.x; zReg[rt][1] = zv.y; zReg[rt][2] = zv.z; zReg[rt][3] = zv.w;
        *(uint2_a*)&Wv.zt[rt][j2 * 40 + g4] = (uint2v){pk2(zv.x, zv.y), pk2(zv.z, zv.w)};
    }
    __syncthreads();

#pragma unroll 1
    for (int pass = 0; pass < 2; ++pass) {
        bf16x8 bZ0 = ldsA(Wv.zt[0], 40, lane, 0);
        bf16x8 bZ1 = ldsA(Wv.zt[1], 40, lane, 0);
        float dzAcc[2][4], fvReg[2][4];

        // ---- step1: t1 = tanh(Wh1 z + bh1) ----
#pragma unroll 2
        for (int nt = 0; nt < 8; ++nt) {
            bf16x8 wt = wsB(ws, T_WH1 + nt, lane);
            PRIO_HI();
            f32x4 a0 = MFMA(wt, bZ0, Z4());
            f32x4 a1 = MFMA(wt, bZ1, Z4());
            PRIO_LO();
            *(uint2_a*)&t1p[0][j2 * 136 + nt * 16 + g4] =
                (uint2v){pk2(ftanh(a0[0]), ftanh(a0[1])), pk2(ftanh(a0[2]), ftanh(a0[3]))};
            *(uint2_a*)&t1p[1][j2 * 136 + nt * 16 + g4] =
                (uint2v){pk2(ftanh(a1[0]), ftanh(a1[1])), pk2(ftanh(a1[2]), ftanh(a1[3]))};
        }
        // ---- step2: fv = mu z + Wh2 t1 ----
        {
            f32x4 a0 = Z4(), a1 = Z4();
#pragma unroll 2
            for (int kt = 0; kt < 4; ++kt) {
                bf16x8 wt = wsB(ws, T_WH2 + kt, lane);
                PRIO_HI();
                a0 = MFMA(wt, ldsA(t1p[0], 136, lane, kt * 32), a0);
                a1 = MFMA(wt, ldsA(t1p[1], 136, lane, kt * 32), a1);
                PRIO_LO();
            }
#pragma unroll
            for (int r = 0; r < 4; ++r) {
                fvReg[0][r] = a0[r] + MU_C * zReg[0][r];
                fvReg[1][r] = a1[r] + MU_C * zReg[1][r];
            }
            *(uint2_a*)&Wv.fvt[0][j2 * 40 + g4] =
                (uint2v){pk2(fvReg[0][0], fvReg[0][1]), pk2(fvReg[0][2], fvReg[0][3])};
            *(uint2_a*)&Wv.fvt[1][j2 * 40 + g4] =
                (uint2v){pk2(fvReg[1][0], fvReg[1][1]), pk2(fvReg[1][2], fvReg[1][3])};
        }
        // ---- step3: s = (1-t1^2) * (Wh2^T fv) ----
        {
            bf16x8 bF0 = ldsA(Wv.fvt[0], 40, lane, 0);
            bf16x8 bF1 = ldsA(Wv.fvt[1], 40, lane, 0);
#pragma unroll 2
            for (int nt = 0; nt < 8; ++nt) {
                bf16x8 wt = wsB(ws, T_WH2T + nt, lane);
                PRIO_HI();
                f32x4 a0 = MFMA(wt, bF0, Z4());
                f32x4 a1 = MFMA(wt, bF1, Z4());
                PRIO_LO();
#pragma unroll
                for (int rt = 0; rt < 2; ++rt) {
                    f32x4 aa = rt ? a1 : a0;
                    uint2v tp = *(const uint2_a*)&t1p[rt][j2 * 136 + nt * 16 + g4];
                    float t0 = bf2f(tp[0] & 0xffffu), t1v = bf2f(tp[0] >> 16);
                    float t2 = bf2f(tp[1] & 0xffffu), t3 = bf2f(tp[1] >> 16);
                    *(uint2_a*)&t1p[rt][j2 * 136 + nt * 16 + g4] =
                        (uint2v){pk2((1.f - t0 * t0) * aa[0], (1.f - t1v * t1v) * aa[1]),
                                 pk2((1.f - t2 * t2) * aa[2], (1.f - t3 * t3) * aa[3])};
                }
            }
        }
        // ---- step4: gH = mu fv + Wh1^T s ----
        {
            f32x4 a0 = Z4(), a1 = Z4();
#pragma unroll 2
            for (int kt = 0; kt < 4; ++kt) {
                bf16x8 wt = wsB(ws, T_WH1T + kt, lane);
                PRIO_HI();
                a0 = MFMA(wt, ldsA(t1p[0], 136, lane, kt * 32), a0);
                a1 = MFMA(wt, ldsA(t1p[1], 136, lane, kt * 32), a1);
                PRIO_LO();
            }
#pragma unroll
            for (int rt = 0; rt < 2; ++rt) {
                f32x4 aa = rt ? a1 : a0;
                float gh0 = aa[0] + MU_C * fvReg[rt][0], gh1 = aa[1] + MU_C * fvReg[rt][1];
                float gh2 = aa[2] + MU_C * fvReg[rt][2], gh3 = aa[3] + MU_C * fvReg[rt][3];
                *(f32x4_a*)&Wv.gHf[rt][j2 * 20 + g4] = (f32x4){gh0, gh1, gh2, gh3};
                *(uint2_a*)&Wv.fvt[rt][j2 * 40 + g4] = (uint2v){pk2(gh0, gh1), pk2(gh2, gh3)};
                dzAcc[rt][0] = -EPS_C * gh0; dzAcc[rt][1] = -EPS_C * gh1;
                dzAcc[rt][2] = -EPS_C * gh2; dzAcc[rt][3] = -EPS_C * gh3;
            }
        }
        // ---- step5: h1 = tanh(W1jr z + b1jr) ----
#pragma unroll 2
        for (int nt = 0; nt < 4; ++nt) {
            bf16x8 wt = wsB(ws, T_W1JR + nt, lane);
            PRIO_HI();
            f32x4 a0 = MFMA(wt, bZ0, Z4());
            f32x4 a1 = MFMA(wt, bZ1, Z4());
            PRIO_LO();
            *(uint2_a*)&h1p[0][j2 * 72 + nt * 16 + g4] =
                (uint2v){pk2(ftanh(a0[0]), ftanh(a0[1])), pk2(ftanh(a0[2]), ftanh(a0[3]))};
            *(uint2_a*)&h1p[1][j2 * 72 + nt * 16 + g4] =
                (uint2v){pk2(ftanh(a1[0]), ftanh(a1[1])), pk2(ftanh(a1[2]), ftanh(a1[3]))};
        }
        // ---- step6: h2 = tanh(W2jr h1 + b2jr) ----
        {
            bf16x8 c00 = ldsA(h1p[0], 72, lane, 0), c01 = ldsA(h1p[0], 72, lane, 32);
            bf16x8 c10 = ldsA(h1p[1], 72, lane, 0), c11 = ldsA(h1p[1], 72, lane, 32);
#pragma unroll 2
            for (int nt = 0; nt < 4; ++nt) {
                bf16x8 w0 = wsB(ws, T_W2JR + nt * 2 + 0, lane);
                bf16x8 w1 = wsB(ws, T_W2JR + nt * 2 + 1, lane);
                PRIO_HI();
                f32x4 a0 = MFMA(w1, c01, MFMA(w0, c00, Z4()));
                f32x4 a1 = MFMA(w1, c11, MFMA(w0, c10, Z4()));
                PRIO_LO();
#pragma unroll
                for (int rt = 0; rt < 2; ++rt) {
                    f32x4 aa = rt ? a1 : a0;
                    *(uint2_a*)&h2p[rt][j2 * 72 + nt * 16 + g4] =
                        (uint2v){pk2(ftanh(aa[0] + L.bias[nt * 16 + g4 + 0]),
                                     ftanh(aa[1] + L.bias[nt * 16 + g4 + 1])),
                                 pk2(ftanh(aa[2] + L.bias[nt * 16 + g4 + 2]),
                                     ftanh(aa[3] + L.bias[nt * 16 + g4 + 3]))};
                }
            }
        }
        // ---- step7: dz += (J - R) gH ----
        {
            bf16x8 h00 = ldsA(h2p[0], 72, lane, 0), h01 = ldsA(h2p[0], 72, lane, 32);
            bf16x8 h10 = ldsA(h2p[1], 72, lane, 0), h11 = ldsA(h2p[1], 72, lane, 32);
            bf16x8 bG0 = ldsA(Wv.fvt[0], 40, lane, 0);
            bf16x8 bG1 = ldsA(Wv.fvt[1], 40, lane, 0);
            {
                bf16x8 wn = wsB(ws, T_JBN, lane);
                bf16x8 wtt = wsB(ws, T_JBT, lane);
                PRIO_HI();
                f32x4 bn0 = MFMA(wn, bG0, Z4());
                f32x4 bn1 = MFMA(wn, bG1, Z4());
                f32x4 bt0 = MFMA(wtt, bG0, Z4());
                f32x4 bt1 = MFMA(wtt, bG1, Z4());
                PRIO_LO();
#pragma unroll
                for (int r = 0; r < 4; ++r) {
                    dzAcc[0][r] += bt0[r] - bn0[r];
                    dzAcc[1][r] += bt1[r] - bn1[r];
                }
            }
            // Jm normal: dz_j -= Jm[n][j] gH[n]
#pragma unroll 2
            for (int n = 0; n < 16; ++n) {
                bf16x8 w0 = wsB(ws, T_JMN + 2 * n + 0, lane);
                bf16x8 w1 = wsB(ws, T_JMN + 2 * n + 1, lane);
                PRIO_HI();
                f32x4 a0 = MFMA(w1, h01, MFMA(w0, h00, Z4()));
                f32x4 a1 = MFMA(w1, h11, MFMA(w0, h10, Z4()));
                PRIO_LO();
                float gA = *(const f32_a*)&Wv.gHf[0][j2 * 20 + n];
                float gB = *(const f32_a*)&Wv.gHf[1][j2 * 20 + n];
#pragma unroll
                for (int r = 0; r < 4; ++r) {
                    dzAcc[0][r] -= a0[r] * gA;
                    dzAcc[1][r] -= a1[r] * gB;
                }
            }
            // Jm transposed: dz_i += Jm[i][t] gH[t]
#pragma unroll 2
            for (int t = 0; t < 16; ++t) {
                bf16x8 w0 = wsB(ws, T_JMT + 2 * t + 0, lane);
                bf16x8 w1 = wsB(ws, T_JMT + 2 * t + 1, lane);
                PRIO_HI();
                f32x4 a0 = MFMA(w1, h01, MFMA(w0, h00, Z4()));
                f32x4 a1 = MFMA(w1, h11, MFMA(w0, h10, Z4()));
                PRIO_LO();
                float gA = *(const f32_a*)&Wv.gHf[0][j2 * 20 + t];
                float gB = *(const f32_a*)&Wv.gHf[1][j2 * 20 + t];
#pragma unroll
                for (int r = 0; r < 4; ++r) {
                    dzAcc[0][r] += a0[r] * gA;
                    dzAcc[1][r] += a1[r] * gB;
                }
            }
            // Rf normal: rfv_j = Rf[n][j] gH[n] (+bias fold)
            {
                float rA[2][4] = {{0.f, 0.f, 0.f, 0.f}, {0.f, 0.f, 0.f, 0.f}};
#pragma unroll 2
                for (int n = 0; n < 16; ++n) {
                    bf16x8 w0 = wsB(ws, T_RFN + 2 * n + 0, lane);
                    bf16x8 w1 = wsB(ws, T_RFN + 2 * n + 1, lane);
                    PRIO_HI();
                    f32x4 a0 = MFMA(w1, h01, MFMA(w0, h00, Z4()));
                    f32x4 a1 = MFMA(w1, h11, MFMA(w0, h10, Z4()));
                    PRIO_LO();
                    float gA = *(const f32_a*)&Wv.gHf[0][j2 * 20 + n];
                    float gB = *(const f32_a*)&Wv.gHf[1][j2 * 20 + n];
#pragma unroll
                    for (int r = 0; r < 4; ++r) {
                        rA[0][r] += a0[r] * gA;
                        rA[1][r] += a1[r] * gB;
                    }
                }
                bf16x8 wrb = wsB(ws, T_RBN, lane);
                PRIO_HI();
                f32x4 rb0 = MFMA(wrb, bG0, Z4());
                f32x4 rb1 = MFMA(wrb, bG1, Z4());
                PRIO_LO();
                *(uint2_a*)&rfp[0][j2 * 40 + g4] =
                    (uint2v){pk2(rA[0][0] + rb0[0], rA[0][1] + rb0[1]),
                             pk2(rA[0][2] + rb0[2], rA[0][3] + rb0[3])};
                *(uint2_a*)&rfp[1][j2 * 40 + g4] =
                    (uint2v){pk2(rA[1][0] + rb1[0], rA[1][1] + rb1[1]),
                             pk2(rA[1][2] + rb1[2], rA[1][3] + rb1[3])};
                if (lane < 16) {
#pragma unroll
                    for (int rt = 0; rt < 2; ++rt) {
                        u32_a* p = (u32_a*)&rfp[rt][lane * 40 + 16];
#pragma unroll
                        for (int i = 0; i < 8; ++i) p[i] = 0u;
                    }
                }
            }
            // Rf transposed bias fold + slabs: dz_i -= Rf[i][t] rfv[t]
            {
                bf16x8 wrt = wsB(ws, T_RBT, lane);
                PRIO_HI();
                f32x4 rtb0 = MFMA(wrt, ldsA(rfp[0], 40, lane, 0), Z4());
                f32x4 rtb1 = MFMA(wrt, ldsA(rfp[1], 40, lane, 0), Z4());
                PRIO_LO();
#pragma unroll
                for (int r = 0; r < 4; ++r) {
                    dzAcc[0][r] -= rtb0[r];
                    dzAcc[1][r] -= rtb1[r];
                }
            }
#pragma unroll 2
            for (int t = 0; t < 16; ++t) {
                bf16x8 w0 = wsB(ws, T_RFT + 2 * t + 0, lane);
                bf16x8 w1 = wsB(ws, T_RFT + 2 * t + 1, lane);
                PRIO_HI();
                f32x4 a0 = MFMA(w1, h01, MFMA(w0, h00, Z4()));
                f32x4 a1 = MFMA(w1, h11, MFMA(w0, h10, Z4()));
                PRIO_LO();
                float rvA = bf2f(*(const u16_a*)&rfp[0][j2 * 40 + t]);
                float rvB = bf2f(*(const u16_a*)&rfp[1][j2 * 40 + t]);
#pragma unroll
                for (int r = 0; r < 4; ++r) {
                    dzAcc[0][r] -= a0[r] * rvA;
                    dzAcc[1][r] -= a1[r] * rvB;
                }
            }
        }
        // ---- step8: g1,g2 (B-net) ----
#pragma unroll 2
        for (int nt = 0; nt < 4; ++nt) {
            bf16x8 wt = wsB(ws, T_W1B + nt, lane);
            PRIO_HI();
            f32x4 a0 = MFMA(wt, bZ0, Z4());
            f32x4 a1 = MFMA(wt, bZ1, Z4());
            PRIO_LO();
            *(uint2_a*)&h1p[0][j2 * 72 + nt * 16 + g4] =
                (uint2v){pk2(ftanh(a0[0]), ftanh(a0[1])), pk2(ftanh(a0[2]), ftanh(a0[3]))};
            *(uint2_a*)&h1p[1][j2 * 72 + nt * 16 + g4] =
                (uint2v){pk2(ftanh(a1[0]), ftanh(a1[1])), pk2(ftanh(a1[2]), ftanh(a1[3]))};
        }
        {
            bf16x8 c00 = ldsA(h1p[0], 72, lane, 0), c01 = ldsA(h1p[0], 72, lane, 32);
            bf16x8 c10 = ldsA(h1p[1], 72, lane, 0), c11 = ldsA(h1p[1], 72, lane, 32);
#pragma unroll 2
            for (int nt = 0; nt < 4; ++nt) {
                bf16x8 w0 = wsB(ws, T_W2B + nt * 2 + 0, lane);
                bf16x8 w1 = wsB(ws, T_W2B + nt * 2 + 1, lane);
                PRIO_HI();
                f32x4 a0 = MFMA(w1, c01, MFMA(w0, c00, Z4()));
                f32x4 a1 = MFMA(w1, c11, MFMA(w0, c10, Z4()));
                PRIO_LO();
#pragma unroll
                for (int rt = 0; rt < 2; ++rt) {
                    f32x4 aa = rt ? a1 : a0;
                    *(uint2_a*)&h2p[rt][j2 * 72 + nt * 16 + g4] =
                        (uint2v){pk2(ftanh(aa[0] + L.bias[64 + nt * 16 + g4 + 0]),
                                     ftanh(aa[1] + L.bias[64 + nt * 16 + g4 + 1])),
                                 pk2(ftanh(aa[2] + L.bias[64 + nt * 16 + g4 + 2]),
                                     ftanh(aa[3] + L.bias[64 + nt * 16 + g4 + 3]))};
                }
            }
        }
        // ---- step9: y and Bu ----
        float yAcc[2][4];
        {
            bf16x8 h00 = ldsA(h2p[0], 72, lane, 0), h01 = ldsA(h2p[0], 72, lane, 32);
            bf16x8 h10 = ldsA(h2p[1], 72, lane, 0), h11 = ldsA(h2p[1], 72, lane, 32);
            bf16x8 bG0 = ldsA(Wv.fvt[0], 40, lane, 0);
            bf16x8 bG1 = ldsA(Wv.fvt[1], 40, lane, 0);
            bf16x8 wbb = wsB(ws, T_BBN, lane);
            PRIO_HI();
            f32x4 yb0 = MFMA(wbb, bG0, Z4());
            f32x4 yb1 = MFMA(wbb, bG1, Z4());
            PRIO_LO();
#pragma unroll
            for (int r = 0; r < 4; ++r) {
                yAcc[0][r] = yb0[r];
                yAcc[1][r] = yb1[r];
            }
#pragma unroll 2
            for (int n = 0; n < 8; ++n) {
                bf16x8 w0 = wsB(ws, T_BMN + 2 * n + 0, lane);
                bf16x8 w1 = wsB(ws, T_BMN + 2 * n + 1, lane);
                PRIO_HI();
                f32x4 a0 = MFMA(w1, h01, MFMA(w0, h00, Z4()));
                f32x4 a1 = MFMA(w1, h11, MFMA(w0, h10, Z4()));
                PRIO_LO();
                float gA = *(const f32_a*)&Wv.gHf[0][j2 * 20 + 2 * n + (g >> 1)];
                float gB = *(const f32_a*)&Wv.gHf[1][j2 * 20 + 2 * n + (g >> 1)];
#pragma unroll
                for (int r = 0; r < 4; ++r) {
                    yAcc[0][r] += a0[r] * gA;
                    yAcc[1][r] += a1[r] * gB;
                }
            }
#pragma unroll 2
            for (int m = 0; m < 8; ++m) {
                bf16x8 w0 = wsB(ws, T_BMT + 2 * m + 0, lane);
                bf16x8 w1 = wsB(ws, T_BMT + 2 * m + 1, lane);
                PRIO_HI();
                f32x4 a0 = MFMA(w1, h01, MFMA(w0, h00, Z4()));
                f32x4 a1 = MFMA(w1, h11, MFMA(w0, h10, Z4()));
                PRIO_LO();
                float uA = *(const f32_a*)&Wv.uf[0][j2 * 9 + m];
                float uB = *(const f32_a*)&Wv.uf[1][j2 * 9 + m];
#pragma unroll
                for (int r = 0; r < 4; ++r) {
                    float bb = L.bias[128 + (g4 + r) * 8 + m];
                    dzAcc[0][r] += (a0[r] + bb) * uA;
                    dzAcc[1][r] += (a1[r] + bb) * uB;
                }
            }
        }
        // ---- pass epilogue ----
#pragma unroll
        for (int rt = 0; rt < 2; ++rt) {
            float* op = out + (size_t)(rowbase + rt * 16 + j2) * 16 + g4;
            if (pass == 0) {
                float4 o;
                o.x = zReg[rt][0] + 0.5f * dzAcc[rt][0];
                o.y = zReg[rt][1] + 0.5f * dzAcc[rt][1];
                o.z = zReg[rt][2] + 0.5f * dzAcc[rt][2];
                o.w = zReg[rt][3] + 0.5f * dzAcc[rt][3];
                *reinterpret_cast<float4*>(op) = o;
#pragma unroll
                for (int r = 0; r < 4; ++r) zReg[rt][r] += dzAcc[rt][r];
                *(uint2_a*)&Wv.zt[rt][j2 * 40 + g4] =
                    (uint2v){pk2(zReg[rt][0], zReg[rt][1]), pk2(zReg[rt][2], zReg[rt][3])};
            } else {
                float4 o = *reinterpret_cast<const float4*>(op);
                o.x += 0.5f * dzAcc[rt][0]; o.y += 0.5f * dzAcc[rt][1];
                o.z += 0.5f * dzAcc[rt][2]; o.w += 0.5f * dzAcc[rt][3];
                *reinterpret_cast<float4*>(op) = o;
                float yv0 = yAcc[rt][0] + __shfl_xor(yAcc[rt][0], 32);
                float yv1 = yAcc[rt][1] + __shfl_xor(yAcc[rt][1], 32);
                float yv2 = yAcc[rt][2] + __shfl_xor(yAcc[rt][2], 32);
                float yv3 = yAcc[rt][3] + __shfl_xor(yAcc[rt][3], 32);
                if (g < 2) {
                    float4 ys; ys.x = yv0; ys.y = yv1; ys.z = yv2; ys.w = yv3;
                    *reinterpret_cast<float4*>(out + (size_t)B * 16 +
                        (size_t)(rowbase + rt * 16 + j2) * 8 + g4) = ys;
                }
            }
        }
    }
}

extern "C" void kernel_launch(void* const* d_in, const int* in_sizes, int n_in,
                              void* d_out, int out_size, void* d_ws, size_t ws_size,
                              hipStream_t stream) {
    const float* zg   = (const float*)d_in[0];
    const float* ug   = (const float*)d_in[1];
    const float* Wh1  = (const float*)d_in[2];
    const float* bh1  = (const float*)d_in[3];
    const float* Wh2  = (const float*)d_in[4];
    const float* W1jr = (const float*)d_in[5];
    const float* b1jr = (const float*)d_in[6];
    const float* W2jr = (const float*)d_in[7];
    const float* b2jr = (const float*)d_in[8];
    const float* W3jr = (const float*)d_in[9];
    const float* b3jr = (const float*)d_in[10];
    const float* W1b  = (const float*)d_in[11];
    const float* b1b  = (const float*)d_in[12];
    const float* W2b  = (const float*)d_in[13];
    const float* b2b  = (const float*)d_in[14];
    const float* W3b  = (const float*)d_in[15];
    const float* b3b  = (const float*)d_in[16];

    short* ws = (short*)d_ws;                       // 213 KB
    const int B = in_sizes[0] / 16;

    hipLaunchKernelGGL(pack_weights, dim3((NTILES * 64 + 255) / 256), dim3(256), 0, stream,
                       Wh1, bh1, Wh2, W1jr, b1jr, W2jr, W3jr, b3jr,
                       W1b, b1b, W2b, W3b, b3b, ws);

    const int grid = (B + 127) / 128;               // 128 rows/block (4 waves x 32)
    hipLaunchKernelGGL(ph_mfma_kernel, dim3(grid), dim3(THREADS), 0, stream,
                       zg, ug, b2jr, b2b, b3b, ws, (float*)d_out, B);
}

// Round 16
// 104.218 us; speedup vs baseline: 1.1755x; 1.1755x over previous
//
#include <hip/hip_runtime.h>

#define THREADS 256
#define MU_C  0.1f
#define EPS_C 0.01f

typedef short bf16x8 __attribute__((ext_vector_type(8)));
typedef bf16x8 bf16x8_a __attribute__((may_alias));
typedef float f32x4 __attribute__((ext_vector_type(4)));
typedef f32x4 f32x4_a __attribute__((may_alias));
typedef float f32_a __attribute__((may_alias));
typedef unsigned uint2v __attribute__((ext_vector_type(2)));
typedef uint2v uint2_a __attribute__((may_alias));
typedef unsigned u32_a __attribute__((may_alias));
typedef unsigned short u16_a __attribute__((may_alias));

__device__ __forceinline__ f32x4 MFMA(bf16x8 a, bf16x8 b, f32x4 c) {
    return __builtin_amdgcn_mfma_f32_16x16x32_bf16(a, b, c, 0, 0, 0);
}
__device__ __forceinline__ f32x4 Z4() { f32x4 z = {0.f, 0.f, 0.f, 0.f}; return z; }

// ---- prepacked tile enumeration (1 tile = 64 lanes x 16B = 1 KB in d_ws) ----
#define T_WH1   0
#define T_WH2   8
#define T_WH2T  12
#define T_WH1T  20
#define T_W1JR  24
#define T_W2JR  28
#define T_JMN   36
#define T_JMT   68
#define T_RFN   100
#define T_RFT   132
#define T_W1B   164
#define T_W2B   168
#define T_BMN   176
#define T_BMT   192
#define T_JBN   208
#define T_JBT   209
#define T_RBN   210
#define T_RBT   211
#define T_BBN   212
#define NTILES  213

__device__ __forceinline__ float ftanh(float x) {
    float e = __builtin_amdgcn_exp2f(x * 2.88539008177792681472f);
    return 1.0f - 2.0f * __builtin_amdgcn_rcpf(e + 1.0f);
}
__device__ __forceinline__ short bfrn(float f) {
    unsigned u = __float_as_uint(f);
    return (short)((u + 0x8000u) >> 16);
}
__device__ __forceinline__ float bf2f(unsigned lo16) {
    return __uint_as_float(lo16 << 16);
}
__device__ __forceinline__ unsigned pk2(float lo, float hi) {
    return ((unsigned)(unsigned short)bfrn(hi) << 16) | (unsigned short)bfrn(lo);
}
__device__ __forceinline__ bf16x8 wsB(const short* __restrict__ ws, int tile, int lane) {
    return *reinterpret_cast<const bf16x8*>(ws + (size_t)((tile << 6) + lane) * 8);
}
__device__ __forceinline__ bf16x8 ldsA(const short* base, int strideS, int lane, int k0) {
    return *reinterpret_cast<const bf16x8_a*>(base + (lane & 15) * strideS + k0 + (lane >> 4) * 8);
}

// ==================== weight pre-pack kernel ====================
__global__ __launch_bounds__(256)
void pack_weights(const float* __restrict__ Wh1, const float* __restrict__ bh1,
                  const float* __restrict__ Wh2,
                  const float* __restrict__ W1jr, const float* __restrict__ b1jr,
                  const float* __restrict__ W2jr, const float* __restrict__ W3jr,
                  const float* __restrict__ b3jr,
                  const float* __restrict__ W1b, const float* __restrict__ b1b,
                  const float* __restrict__ W2b, const float* __restrict__ W3b,
                  const float* __restrict__ b3b,
                  short* __restrict__ ws)
{
    const int id = blockIdx.x * 256 + threadIdx.x;
    if (id >= NTILES * 64) return;
    const int tile = id >> 6, lane = id & 63;
    const int j2 = lane & 15, g = lane >> 4;
    bf16x8 f;
#pragma unroll
    for (int jj = 0; jj < 8; ++jj) {
        const int k = g * 8 + jj;
        float x = 0.f;
        if (tile < T_WH2) {
            int n0 = (tile - T_WH1) * 16;
            if (g < 2) x = Wh1[(n0 + j2) * 16 + k];
            else if (k == 16) x = bh1[n0 + j2];
        } else if (tile < T_WH2T) {
            int kt = tile - T_WH2;
            x = Wh2[j2 * 128 + kt * 32 + k];
        } else if (tile < T_WH1T) {
            if (g < 2) x = Wh2[k * 128 + (tile - T_WH2T) * 16 + j2];
        } else if (tile < T_W1JR) {
            int kt = tile - T_WH1T;
            x = Wh1[(kt * 32 + k) * 16 + j2];
        } else if (tile < T_W2JR) {
            int n0 = (tile - T_W1JR) * 16;
            if (g < 2) x = W1jr[(n0 + j2) * 16 + k];
            else if (k == 16) x = b1jr[n0 + j2];
        } else if (tile < T_JMN) {
            int q = tile - T_W2JR; int nt = q >> 1, kt = q & 1;
            x = W2jr[(nt * 16 + j2) * 64 + kt * 32 + k];
        } else if (tile < T_JMT) {
            int q = tile - T_JMN; int n = q >> 1, kt = q & 1;
            x = W3jr[(n * 16 + j2) * 64 + kt * 32 + k];
        } else if (tile < T_RFN) {
            int q = tile - T_JMT; int t = q >> 1, kt = q & 1;
            x = W3jr[(j2 * 16 + t) * 64 + kt * 32 + k];
        } else if (tile < T_RFT) {
            int q = tile - T_RFN; int n = q >> 1, kt = q & 1;
            x = W3jr[(256 + n * 16 + j2) * 64 + kt * 32 + k];
        } else if (tile < T_W1B) {
            int q = tile - T_RFT; int t = q >> 1, kt = q & 1;
            x = W3jr[(256 + j2 * 16 + t) * 64 + kt * 32 + k];
        } else if (tile < T_W2B) {
            int n0 = (tile - T_W1B) * 16;
            if (g < 2) x = W1b[(n0 + j2) * 16 + k];
            else if (k == 16) x = b1b[n0 + j2];
        } else if (tile < T_BMN) {
            int q = tile - T_W2B; int nt = q >> 1, kt = q & 1;
            x = W2b[(nt * 16 + j2) * 64 + kt * 32 + k];
        } else if (tile < T_BMT) {
            int q = tile - T_BMN; int n = q >> 1, kt = q & 1;
            x = W3b[(n * 16 + j2) * 64 + kt * 32 + k];
        } else if (tile < T_JBN) {
            int q = tile - T_BMT; int m = q >> 1, kt = q & 1;
            x = W3b[(j2 * 8 + m) * 64 + kt * 32 + k];
        } else if (tile == T_JBN) {
            if (k < 16) x = b3jr[k * 16 + j2];
        } else if (tile == T_JBT) {
            if (k < 16) x = b3jr[j2 * 16 + k];
        } else if (tile == T_RBN) {
            if (k < 16) x = b3jr[256 + k * 16 + j2];
        } else if (tile == T_RBT) {
            if (k < 16) x = b3jr[256 + j2 * 16 + k];
        } else {  // T_BBN
            if (k < 16 && j2 < 8) x = b3b[k * 8 + j2];
        }
        f[jj] = bfrn(x);
    }
    reinterpret_cast<bf16x8*>(ws)[id] = f;
}

// ==================== main kernel: M=32 rows per wave (r12 champion) ========
// Each wave owns TWO 16-row tiles (rt=0,1); every weight tile is loaded from
// L2 ONCE and feeds 2 MFMAs.
struct __align__(16) WaveLds {
    short zt [2][16 * 40];
    short fvt[2][16 * 40];   // fv; reused as gH bf16 tile after step4
    char  act[2][4608];      // t1[16][136]s | {h1t/rft, h2t @2304}
    float gHf[2][16 * 20];
    float uf [2][16 * 9];
};
struct __align__(16) BlockLds {
    WaveLds w[4];
    float bias[256];         // 0 b2jr(64) | 64 b2b(64) | 128 b3b(128)
};

// Final config ledger: (2,4) -> 88 VGPR no-spill; unroll2 (unroll4 spills);
// 4x32-row waves (2-wave blocks regressed); no setprio (regressed);
// gHf f32 (bf16-scalar variant regressed).
__global__ __launch_bounds__(THREADS)
__attribute__((amdgpu_waves_per_eu(2, 4)))
void ph_mfma_kernel(const float* __restrict__ zg, const float* __restrict__ ug,
                    const float* __restrict__ b2jr, const float* __restrict__ b2b,
                    const float* __restrict__ b3b,
                    const short* __restrict__ ws,
                    float* __restrict__ out, int B)
{
    __shared__ BlockLds L;
    const int tid  = threadIdx.x;
    const int lane = tid & 63;
    const int wid  = tid >> 6;
    const int j2   = lane & 15;
    const int g    = lane >> 4;
    const int g4   = g * 4;
    const int rowbase = blockIdx.x * 128 + wid * 32;
    if (blockIdx.x * 128 >= B) return;

    WaveLds& Wv = L.w[wid];
    short* t1p[2] = {(short*)Wv.act[0], (short*)Wv.act[1]};             // stride 136
    short* h1p[2] = {(short*)Wv.act[0], (short*)Wv.act[1]};             // stride 72
    short* h2p[2] = {(short*)(Wv.act[0] + 2304), (short*)(Wv.act[1] + 2304)};
    short* rfp[2] = {(short*)Wv.act[0], (short*)Wv.act[1]};             // stride 40

    // ---- block prologue: biases ----
    if (tid < 256) {
        float v;
        if      (tid < 64)  v = b2jr[tid];
        else if (tid < 128) v = b2b[tid - 64];
        else                v = b3b[tid - 128];
        L.bias[tid] = v;
    }
    // ---- per-wave prologue ----
    if (lane < 16) {
#pragma unroll
        for (int rt = 0; rt < 2; ++rt) {
            u32_a* p = (u32_a*)&Wv.zt[rt][lane * 40 + 16];
            p[0] = 0x00003F80u;
#pragma unroll
            for (int i = 1; i < 8; ++i) p[i] = 0u;
            u32_a* q = (u32_a*)&Wv.fvt[rt][lane * 40 + 16];
#pragma unroll
            for (int i = 0; i < 8; ++i) q[i] = 0u;
        }
    }
    for (int i = lane; i < 256; i += 64) {      // u for both row-tiles
        int rt = i >> 7, r = (i >> 3) & 15, m = i & 7;
        Wv.uf[rt][r * 9 + m] = ug[(size_t)(rowbase + rt * 16 + r) * 8 + m];
    }
    float zReg[2][4];
#pragma unroll
    for (int rt = 0; rt < 2; ++rt) {
        float4 zv = *reinterpret_cast<const float4*>(zg + (size_t)(rowbase + rt * 16 + j2) * 16 + g4);
        zReg[rt][0] = zv.x; zReg[rt][1] = zv.y; zReg[rt][2] = zv.z; zReg[rt][3] = zv.w;
        *(uint2_a*)&Wv.zt[rt][j2 * 40 + g4] = (uint2v){pk2(zv.x, zv.y), pk2(zv.z, zv.w)};
    }
    __syncthreads();

#pragma unroll 1
    for (int pass = 0; pass < 2; ++pass) {
        bf16x8 bZ0 = ldsA(Wv.zt[0], 40, lane, 0);
        bf16x8 bZ1 = ldsA(Wv.zt[1], 40, lane, 0);
        float dzAcc[2][4], fvReg[2][4];

        // ---- step1: t1 = tanh(Wh1 z + bh1) ----
#pragma unroll 2
        for (int nt = 0; nt < 8; ++nt) {
            bf16x8 wt = wsB(ws, T_WH1 + nt, lane);
            f32x4 a0 = MFMA(wt, bZ0, Z4());
            f32x4 a1 = MFMA(wt, bZ1, Z4());
            *(uint2_a*)&t1p[0][j2 * 136 + nt * 16 + g4] =
                (uint2v){pk2(ftanh(a0[0]), ftanh(a0[1])), pk2(ftanh(a0[2]), ftanh(a0[3]))};
            *(uint2_a*)&t1p[1][j2 * 136 + nt * 16 + g4] =
                (uint2v){pk2(ftanh(a1[0]), ftanh(a1[1])), pk2(ftanh(a1[2]), ftanh(a1[3]))};
        }
        // ---- step2: fv = mu z + Wh2 t1 ----
        {
            f32x4 a0 = Z4(), a1 = Z4();
#pragma unroll 2
            for (int kt = 0; kt < 4; ++kt) {
                bf16x8 wt = wsB(ws, T_WH2 + kt, lane);
                a0 = MFMA(wt, ldsA(t1p[0], 136, lane, kt * 32), a0);
                a1 = MFMA(wt, ldsA(t1p[1], 136, lane, kt * 32), a1);
            }
#pragma unroll
            for (int r = 0; r < 4; ++r) {
                fvReg[0][r] = a0[r] + MU_C * zReg[0][r];
                fvReg[1][r] = a1[r] + MU_C * zReg[1][r];
            }
            *(uint2_a*)&Wv.fvt[0][j2 * 40 + g4] =
                (uint2v){pk2(fvReg[0][0], fvReg[0][1]), pk2(fvReg[0][2], fvReg[0][3])};
            *(uint2_a*)&Wv.fvt[1][j2 * 40 + g4] =
                (uint2v){pk2(fvReg[1][0], fvReg[1][1]), pk2(fvReg[1][2], fvReg[1][3])};
        }
        // ---- step3: s = (1-t1^2) * (Wh2^T fv) ----
        {
            bf16x8 bF0 = ldsA(Wv.fvt[0], 40, lane, 0);
            bf16x8 bF1 = ldsA(Wv.fvt[1], 40, lane, 0);
#pragma unroll 2
            for (int nt = 0; nt < 8; ++nt) {
                bf16x8 wt = wsB(ws, T_WH2T + nt, lane);
                f32x4 a0 = MFMA(wt, bF0, Z4());
                f32x4 a1 = MFMA(wt, bF1, Z4());
#pragma unroll
                for (int rt = 0; rt < 2; ++rt) {
                    f32x4 aa = rt ? a1 : a0;
                    uint2v tp = *(const uint2_a*)&t1p[rt][j2 * 136 + nt * 16 + g4];
                    float t0 = bf2f(tp[0] & 0xffffu), t1v = bf2f(tp[0] >> 16);
                    float t2 = bf2f(tp[1] & 0xffffu), t3 = bf2f(tp[1] >> 16);
                    *(uint2_a*)&t1p[rt][j2 * 136 + nt * 16 + g4] =
                        (uint2v){pk2((1.f - t0 * t0) * aa[0], (1.f - t1v * t1v) * aa[1]),
                                 pk2((1.f - t2 * t2) * aa[2], (1.f - t3 * t3) * aa[3])};
                }
            }
        }
        // ---- step4: gH = mu fv + Wh1^T s ----
        {
            f32x4 a0 = Z4(), a1 = Z4();
#pragma unroll 2
            for (int kt = 0; kt < 4; ++kt) {
                bf16x8 wt = wsB(ws, T_WH1T + kt, lane);
                a0 = MFMA(wt, ldsA(t1p[0], 136, lane, kt * 32), a0);
                a1 = MFMA(wt, ldsA(t1p[1], 136, lane, kt * 32), a1);
            }
#pragma unroll
            for (int rt = 0; rt < 2; ++rt) {
                f32x4 aa = rt ? a1 : a0;
                float gh0 = aa[0] + MU_C * fvReg[rt][0], gh1 = aa[1] + MU_C * fvReg[rt][1];
                float gh2 = aa[2] + MU_C * fvReg[rt][2], gh3 = aa[3] + MU_C * fvReg[rt][3];
                *(f32x4_a*)&Wv.gHf[rt][j2 * 20 + g4] = (f32x4){gh0, gh1, gh2, gh3};
                *(uint2_a*)&Wv.fvt[rt][j2 * 40 + g4] = (uint2v){pk2(gh0, gh1), pk2(gh2, gh3)};
                dzAcc[rt][0] = -EPS_C * gh0; dzAcc[rt][1] = -EPS_C * gh1;
                dzAcc[rt][2] = -EPS_C * gh2; dzAcc[rt][3] = -EPS_C * gh3;
            }
        }
        // ---- step5: h1 = tanh(W1jr z + b1jr) ----
#pragma unroll 2
        for (int nt = 0; nt < 4; ++nt) {
            bf16x8 wt = wsB(ws, T_W1JR + nt, lane);
            f32x4 a0 = MFMA(wt, bZ0, Z4());
            f32x4 a1 = MFMA(wt, bZ1, Z4());
            *(uint2_a*)&h1p[0][j2 * 72 + nt * 16 + g4] =
                (uint2v){pk2(ftanh(a0[0]), ftanh(a0[1])), pk2(ftanh(a0[2]), ftanh(a0[3]))};
            *(uint2_a*)&h1p[1][j2 * 72 + nt * 16 + g4] =
                (uint2v){pk2(ftanh(a1[0]), ftanh(a1[1])), pk2(ftanh(a1[2]), ftanh(a1[3]))};
        }
        // ---- step6: h2 = tanh(W2jr h1 + b2jr) ----
        {
            bf16x8 c00 = ldsA(h1p[0], 72, lane, 0), c01 = ldsA(h1p[0], 72, lane, 32);
            bf16x8 c10 = ldsA(h1p[1], 72, lane, 0), c11 = ldsA(h1p[1], 72, lane, 32);
#pragma unroll 2
            for (int nt = 0; nt < 4; ++nt) {
                bf16x8 w0 = wsB(ws, T_W2JR + nt * 2 + 0, lane);
                bf16x8 w1 = wsB(ws, T_W2JR + nt * 2 + 1, lane);
                f32x4 a0 = MFMA(w1, c01, MFMA(w0, c00, Z4()));
                f32x4 a1 = MFMA(w1, c11, MFMA(w0, c10, Z4()));
#pragma unroll
                for (int rt = 0; rt < 2; ++rt) {
                    f32x4 aa = rt ? a1 : a0;
                    *(uint2_a*)&h2p[rt][j2 * 72 + nt * 16 + g4] =
                        (uint2v){pk2(ftanh(aa[0] + L.bias[nt * 16 + g4 + 0]),
                                     ftanh(aa[1] + L.bias[nt * 16 + g4 + 1])),
                                 pk2(ftanh(aa[2] + L.bias[nt * 16 + g4 + 2]),
                                     ftanh(aa[3] + L.bias[nt * 16 + g4 + 3]))};
                }
            }
        }
        // ---- step7: dz += (J - R) gH ----
        {
            bf16x8 h00 = ldsA(h2p[0], 72, lane, 0), h01 = ldsA(h2p[0], 72, lane, 32);
            bf16x8 h10 = ldsA(h2p[1], 72, lane, 0), h11 = ldsA(h2p[1], 72, lane, 32);
            bf16x8 bG0 = ldsA(Wv.fvt[0], 40, lane, 0);
            bf16x8 bG1 = ldsA(Wv.fvt[1], 40, lane, 0);
            {
                bf16x8 wn = wsB(ws, T_JBN, lane);
                bf16x8 wtt = wsB(ws, T_JBT, lane);
                f32x4 bn0 = MFMA(wn, bG0, Z4());
                f32x4 bn1 = MFMA(wn, bG1, Z4());
                f32x4 bt0 = MFMA(wtt, bG0, Z4());
                f32x4 bt1 = MFMA(wtt, bG1, Z4());
#pragma unroll
                for (int r = 0; r < 4; ++r) {
                    dzAcc[0][r] += bt0[r] - bn0[r];
                    dzAcc[1][r] += bt1[r] - bn1[r];
                }
            }
            // Jm normal: dz_j -= Jm[n][j] gH[n]
#pragma unroll 2
            for (int n = 0; n < 16; ++n) {
                bf16x8 w0 = wsB(ws, T_JMN + 2 * n + 0, lane);
                bf16x8 w1 = wsB(ws, T_JMN + 2 * n + 1, lane);
                f32x4 a0 = MFMA(w1, h01, MFMA(w0, h00, Z4()));
                f32x4 a1 = MFMA(w1, h11, MFMA(w0, h10, Z4()));
                float gA = *(const f32_a*)&Wv.gHf[0][j2 * 20 + n];
                float gB = *(const f32_a*)&Wv.gHf[1][j2 * 20 + n];
#pragma unroll
                for (int r = 0; r < 4; ++r) {
                    dzAcc[0][r] -= a0[r] * gA;
                    dzAcc[1][r] -= a1[r] * gB;
                }
            }
            // Jm transposed: dz_i += Jm[i][t] gH[t]
#pragma unroll 2
            for (int t = 0; t < 16; ++t) {
                bf16x8 w0 = wsB(ws, T_JMT + 2 * t + 0, lane);
                bf16x8 w1 = wsB(ws, T_JMT + 2 * t + 1, lane);
                f32x4 a0 = MFMA(w1, h01, MFMA(w0, h00, Z4()));
                f32x4 a1 = MFMA(w1, h11, MFMA(w0, h10, Z4()));
                float gA = *(const f32_a*)&Wv.gHf[0][j2 * 20 + t];
                float gB = *(const f32_a*)&Wv.gHf[1][j2 * 20 + t];
#pragma unroll
                for (int r = 0; r < 4; ++r) {
                    dzAcc[0][r] += a0[r] * gA;
                    dzAcc[1][r] += a1[r] * gB;
                }
            }
            // Rf normal: rfv_j = Rf[n][j] gH[n] (+bias fold)
            {
                float rA[2][4] = {{0.f, 0.f, 0.f, 0.f}, {0.f, 0.f, 0.f, 0.f}};
#pragma unroll 2
                for (int n = 0; n < 16; ++n) {
                    bf16x8 w0 = wsB(ws, T_RFN + 2 * n + 0, lane);
                    bf16x8 w1 = wsB(ws, T_RFN + 2 * n + 1, lane);
                    f32x4 a0 = MFMA(w1, h01, MFMA(w0, h00, Z4()));
                    f32x4 a1 = MFMA(w1, h11, MFMA(w0, h10, Z4()));
                    float gA = *(const f32_a*)&Wv.gHf[0][j2 * 20 + n];
                    float gB = *(const f32_a*)&Wv.gHf[1][j2 * 20 + n];
#pragma unroll
                    for (int r = 0; r < 4; ++r) {
                        rA[0][r] += a0[r] * gA;
                        rA[1][r] += a1[r] * gB;
                    }
                }
                bf16x8 wrb = wsB(ws, T_RBN, lane);
                f32x4 rb0 = MFMA(wrb, bG0, Z4());
                f32x4 rb1 = MFMA(wrb, bG1, Z4());
                *(uint2_a*)&rfp[0][j2 * 40 + g4] =
                    (uint2v){pk2(rA[0][0] + rb0[0], rA[0][1] + rb0[1]),
                             pk2(rA[0][2] + rb0[2], rA[0][3] + rb0[3])};
                *(uint2_a*)&rfp[1][j2 * 40 + g4] =
                    (uint2v){pk2(rA[1][0] + rb1[0], rA[1][1] + rb1[1]),
                             pk2(rA[1][2] + rb1[2], rA[1][3] + rb1[3])};
                if (lane < 16) {
#pragma unroll
                    for (int rt = 0; rt < 2; ++rt) {
                        u32_a* p = (u32_a*)&rfp[rt][lane * 40 + 16];
#pragma unroll
                        for (int i = 0; i < 8; ++i) p[i] = 0u;
                    }
                }
            }
            // Rf transposed bias fold + slabs: dz_i -= Rf[i][t] rfv[t]
            {
                bf16x8 wrt = wsB(ws, T_RBT, lane);
                f32x4 rtb0 = MFMA(wrt, ldsA(rfp[0], 40, lane, 0), Z4());
                f32x4 rtb1 = MFMA(wrt, ldsA(rfp[1], 40, lane, 0), Z4());
#pragma unroll
                for (int r = 0; r < 4; ++r) {
                    dzAcc[0][r] -= rtb0[r];
                    dzAcc[1][r] -= rtb1[r];
                }
            }
#pragma unroll 2
            for (int t = 0; t < 16; ++t) {
                bf16x8 w0 = wsB(ws, T_RFT + 2 * t + 0, lane);
                bf16x8 w1 = wsB(ws, T_RFT + 2 * t + 1, lane);
                f32x4 a0 = MFMA(w1, h01, MFMA(w0, h00, Z4()));
                f32x4 a1 = MFMA(w1, h11, MFMA(w0, h10, Z4()));
                float rvA = bf2f(*(const u16_a*)&rfp[0][j2 * 40 + t]);
                float rvB = bf2f(*(const u16_a*)&rfp[1][j2 * 40 + t]);
#pragma unroll
                for (int r = 0; r < 4; ++r) {
                    dzAcc[0][r] -= a0[r] * rvA;
                    dzAcc[1][r] -= a1[r] * rvB;
                }
            }
        }
        // ---- step8: g1,g2 (B-net) ----
#pragma unroll 2
        for (int nt = 0; nt < 4; ++nt) {
            bf16x8 wt = wsB(ws, T_W1B + nt, lane);
            f32x4 a0 = MFMA(wt, bZ0, Z4());
            f32x4 a1 = MFMA(wt, bZ1, Z4());
            *(uint2_a*)&h1p[0][j2 * 72 + nt * 16 + g4] =
                (uint2v){pk2(ftanh(a0[0]), ftanh(a0[1])), pk2(ftanh(a0[2]), ftanh(a0[3]))};
            *(uint2_a*)&h1p[1][j2 * 72 + nt * 16 + g4] =
                (uint2v){pk2(ftanh(a1[0]), ftanh(a1[1])), pk2(ftanh(a1[2]), ftanh(a1[3]))};
        }
        {
            bf16x8 c00 = ldsA(h1p[0], 72, lane, 0), c01 = ldsA(h1p[0], 72, lane, 32);
            bf16x8 c10 = ldsA(h1p[1], 72, lane, 0), c11 = ldsA(h1p[1], 72, lane, 32);
#pragma unroll 2
            for (int nt = 0; nt < 4; ++nt) {
                bf16x8 w0 = wsB(ws, T_W2B + nt * 2 + 0, lane);
                bf16x8 w1 = wsB(ws, T_W2B + nt * 2 + 1, lane);
                f32x4 a0 = MFMA(w1, c01, MFMA(w0, c00, Z4()));
                f32x4 a1 = MFMA(w1, c11, MFMA(w0, c10, Z4()));
#pragma unroll
                for (int rt = 0; rt < 2; ++rt) {
                    f32x4 aa = rt ? a1 : a0;
                    *(uint2_a*)&h2p[rt][j2 * 72 + nt * 16 + g4] =
                        (uint2v){pk2(ftanh(aa[0] + L.bias[64 + nt * 16 + g4 + 0]),
                                     ftanh(aa[1] + L.bias[64 + nt * 16 + g4 + 1])),
                                 pk2(ftanh(aa[2] + L.bias[64 + nt * 16 + g4 + 2]),
                                     ftanh(aa[3] + L.bias[64 + nt * 16 + g4 + 3]))};
                }
            }
        }
        // ---- step9: y and Bu ----
        float yAcc[2][4];
        {
            bf16x8 h00 = ldsA(h2p[0], 72, lane, 0), h01 = ldsA(h2p[0], 72, lane, 32);
            bf16x8 h10 = ldsA(h2p[1], 72, lane, 0), h11 = ldsA(h2p[1], 72, lane, 32);
            bf16x8 bG0 = ldsA(Wv.fvt[0], 40, lane, 0);
            bf16x8 bG1 = ldsA(Wv.fvt[1], 40, lane, 0);
            bf16x8 wbb = wsB(ws, T_BBN, lane);
            f32x4 yb0 = MFMA(wbb, bG0, Z4());
            f32x4 yb1 = MFMA(wbb, bG1, Z4());
#pragma unroll
            for (int r = 0; r < 4; ++r) {
                yAcc[0][r] = yb0[r];
                yAcc[1][r] = yb1[r];
            }
#pragma unroll 2
            for (int n = 0; n < 8; ++n) {
                bf16x8 w0 = wsB(ws, T_BMN + 2 * n + 0, lane);
                bf16x8 w1 = wsB(ws, T_BMN + 2 * n + 1, lane);
                f32x4 a0 = MFMA(w1, h01, MFMA(w0, h00, Z4()));
                f32x4 a1 = MFMA(w1, h11, MFMA(w0, h10, Z4()));
                float gA = *(const f32_a*)&Wv.gHf[0][j2 * 20 + 2 * n + (g >> 1)];
                float gB = *(const f32_a*)&Wv.gHf[1][j2 * 20 + 2 * n + (g >> 1)];
#pragma unroll
                for (int r = 0; r < 4; ++r) {
                    yAcc[0][r] += a0[r] * gA;
                    yAcc[1][r] += a1[r] * gB;
                }
            }
#pragma unroll 2
            for (int m = 0; m < 8; ++m) {
                bf16x8 w0 = wsB(ws, T_BMT + 2 * m + 0, lane);
                bf16x8 w1 = wsB(ws, T_BMT + 2 * m + 1, lane);
                f32x4 a0 = MFMA(w1, h01, MFMA(w0, h00, Z4()));
                f32x4 a1 = MFMA(w1, h11, MFMA(w0, h10, Z4()));
                float uA = *(const f32_a*)&Wv.uf[0][j2 * 9 + m];
                float uB = *(const f32_a*)&Wv.uf[1][j2 * 9 + m];
#pragma unroll
                for (int r = 0; r < 4; ++r) {
                    float bb = L.bias[128 + (g4 + r) * 8 + m];
                    dzAcc[0][r] += (a0[r] + bb) * uA;
                    dzAcc[1][r] += (a1[r] + bb) * uB;
                }
            }
        }
        // ---- pass epilogue ----
#pragma unroll
        for (int rt = 0; rt < 2; ++rt) {
            float* op = out + (size_t)(rowbase + rt * 16 + j2) * 16 + g4;
            if (pass == 0) {
                float4 o;
                o.x = zReg[rt][0] + 0.5f * dzAcc[rt][0];
                o.y = zReg[rt][1] + 0.5f * dzAcc[rt][1];
                o.z = zReg[rt][2] + 0.5f * dzAcc[rt][2];
                o.w = zReg[rt][3] + 0.5f * dzAcc[rt][3];
                *reinterpret_cast<float4*>(op) = o;
#pragma unroll
                for (int r = 0; r < 4; ++r) zReg[rt][r] += dzAcc[rt][r];
                *(uint2_a*)&Wv.zt[rt][j2 * 40 + g4] =
                    (uint2v){pk2(zReg[rt][0], zReg[rt][1]), pk2(zReg[rt][2], zReg[rt][3])};
            } else {
                float4 o = *reinterpret_cast<const float4*>(op);
                o.x += 0.5f * dzAcc[rt][0]; o.y += 0.5f * dzAcc[rt][1];
                o.z += 0.5f * dzAcc[rt][2]; o.w += 0.5f * dzAcc[rt][3];
                *reinterpret_cast<float4*>(op) = o;
                float yv0 = yAcc[rt][0] + __shfl_xor(yAcc[rt][0], 32);
                float yv1 = yAcc[rt][1] + __shfl_xor(yAcc[rt][1], 32);
                float yv2 = yAcc[rt][2] + __shfl_xor(yAcc[rt][2], 32);
                float yv3 = yAcc[rt][3] + __shfl_xor(yAcc[rt][3], 32);
                if (g < 2) {
                    float4 ys; ys.x = yv0; ys.y = yv1; ys.z = yv2; ys.w = yv3;
                    *reinterpret_cast<float4*>(out + (size_t)B * 16 +
                        (size_t)(rowbase + rt * 16 + j2) * 8 + g4) = ys;
                }
            }
        }
    }
}

extern "C" void kernel_launch(void* const* d_in, const int* in_sizes, int n_in,
                              void* d_out, int out_size, void* d_ws, size_t ws_size,
                              hipStream_t stream) {
    const float* zg   = (const float*)d_in[0];
    const float* ug   = (const float*)d_in[1];
    const float* Wh1  = (const float*)d_in[2];
    const float* bh1  = (const float*)d_in[3];
    const float* Wh2  = (const float*)d_in[4];
    const float* W1jr = (const float*)d_in[5];
    const float* b1jr = (const float*)d_in[6];
    const float* W2jr = (const float*)d_in[7];
    const float* b2jr = (const float*)d_in[8];
    const float* W3jr = (const float*)d_in[9];
    const float* b3jr = (const float*)d_in[10];
    const float* W1b  = (const float*)d_in[11];
    const float* b1b  = (const float*)d_in[12];
    const float* W2b  = (const float*)d_in[13];
    const float* b2b  = (const float*)d_in[14];
    const float* W3b  = (const float*)d_in[15];
    const float* b3b  = (const float*)d_in[16];

    short* ws = (short*)d_ws;                       // 213 KB
    const int B = in_sizes[0] / 16;

    hipLaunchKernelGGL(pack_weights, dim3((NTILES * 64 + 255) / 256), dim3(256), 0, stream,
                       Wh1, bh1, Wh2, W1jr, b1jr, W2jr, W3jr, b3jr,
                       W1b, b1b, W2b, W3b, b3b, ws);

    const int grid = (B + 127) / 128;               // 128 rows/block (4 waves x 32)
    hipLaunchKernelGGL(ph_mfma_kernel, dim3(grid), dim3(THREADS), 0, stream,
                       zg, ug, b2jr, b2b, b3b, ws, (float*)d_out, B);
}